// Round 2
// baseline (65.698 us; speedup 1.0000x reference)
//
#include <hip/hip_runtime.h>
#include <hip/hip_bf16.h>

// Problem constants (B=1, S=5, Q=512, T=64, D=2048)
#define S_DIM 5
#define Q_DIM 512
#define T_DIM 64
#define D_DIM 2048
#define EPS_CS 1e-8f

typedef float f32x4 __attribute__((ext_vector_type(4)));

// Workspace layout (floats):
//   sp    : [S_DIM][D_DIM]   @ 0          (10240)
//   qp    : [Q_DIM][D_DIM]   @ 10240      (1048576)
//   norms : [S_DIM + Q_DIM]  @ 1058816    (517, padded)
//   nll   : [Q_DIM]          @ 1059336    (512)
#define WS_SP    0
#define WS_QP    10240
#define WS_NORMS 1058816
#define WS_NLL   1059336

__device__ __forceinline__ float wave_reduce_sum(float v) {
    #pragma unroll
    for (int off = 32; off > 0; off >>= 1)
        v += __shfl_down(v, off, 64);
    return v;
}

// Kernel A: pool one row (supp row if b<5, else query row) over T.
// Writes pooled vector + its L2 norm. 517 blocks x 512 threads.
__global__ __launch_bounds__(512) void pool_kernel(
    const float* __restrict__ supp, const float* __restrict__ query,
    float* __restrict__ sp, float* __restrict__ qp, float* __restrict__ norms)
{
    const int b   = blockIdx.x;
    const int tid = threadIdx.x;

    const float* src = (b < S_DIM)
        ? supp  + (size_t)b * T_DIM * D_DIM
        : query + (size_t)(b - S_DIM) * T_DIM * D_DIM;
    float* dst = (b < S_DIM)
        ? sp + (size_t)b * D_DIM
        : qp + (size_t)(b - S_DIM) * D_DIM;

    const f32x4* base = (const f32x4*)src;

    f32x4 acc = {0.f, 0.f, 0.f, 0.f};
    #pragma unroll 16
    for (int t = 0; t < T_DIM; ++t) {
        f32x4 v = __builtin_nontemporal_load(&base[t * (D_DIM / 4) + tid]);
        acc += v;
    }
    const float inv = 1.0f / (float)T_DIM;
    acc *= inv;

    ((f32x4*)dst)[tid] = acc;

    float sq = acc.x * acc.x + acc.y * acc.y + acc.z * acc.z + acc.w * acc.w;
    float r = wave_reduce_sum(sq);

    __shared__ float lds[8];
    const int wave = tid >> 6, lane = tid & 63;
    if (lane == 0) lds[wave] = r;
    __syncthreads();
    if (tid == 0) {
        float tot = 0.f;
        #pragma unroll
        for (int w = 0; w < 8; ++w) tot += lds[w];
        norms[b] = sqrtf(tot);
    }
}

// Kernel B: per-q dots vs the 5 sp rows, dist, (1-dist) output, per-q nll.
// 64 blocks x 512 threads; wave w handles q = blockIdx*8 + w.
__global__ __launch_bounds__(512) void dot_kernel(
    const float* __restrict__ sp, const float* __restrict__ qp,
    const float* __restrict__ norms, const int* __restrict__ ys,
    float* __restrict__ out, float* __restrict__ nll)
{
    const int wave = threadIdx.x >> 6;
    const int lane = threadIdx.x & 63;
    const int q    = blockIdx.x * 8 + wave;

    const f32x4* qv4 = (const f32x4*)(qp + (size_t)q * D_DIM);

    float dots[S_DIM];
    #pragma unroll
    for (int s = 0; s < S_DIM; ++s) dots[s] = 0.f;

    #pragma unroll
    for (int i = 0; i < D_DIM / 4 / 64; ++i) {   // 8 iterations
        const int idx = lane + i * 64;
        f32x4 v = qv4[idx];
        #pragma unroll
        for (int s = 0; s < S_DIM; ++s) {
            f32x4 sv = ((const f32x4*)(sp + (size_t)s * D_DIM))[idx];
            dots[s] += v.x * sv.x + v.y * sv.y + v.z * sv.z + v.w * sv.w;
        }
    }

    #pragma unroll
    for (int s = 0; s < S_DIM; ++s)
        dots[s] = wave_reduce_sum(dots[s]);

    if (lane == 0) {
        const float qn = norms[S_DIM + q];
        float dist[S_DIM];
        #pragma unroll
        for (int s = 0; s < S_DIM; ++s) {
            float d = dots[s] / fmaxf(qn * norms[s], EPS_CS);
            dist[s] = d;
            out[1 + (size_t)q * S_DIM + s] = 1.0f - d;
        }
        float m = dist[0];
        #pragma unroll
        for (int s = 1; s < S_DIM; ++s) m = fmaxf(m, dist[s]);
        float sum = 0.f;
        #pragma unroll
        for (int s = 0; s < S_DIM; ++s) sum += expf(dist[s] - m);
        const float lse = m + logf(sum);

        int y = ys[q];
        if (y < 0) y = 0;
        if (y >= S_DIM) y = S_DIM - 1;
        nll[q] = lse - dist[y];
    }
}

// Kernel C: mean of nll over Q -> out[0]. 1 block x 512 threads.
__global__ __launch_bounds__(512) void loss_kernel(
    const float* __restrict__ nll, float* __restrict__ out)
{
    const int q = threadIdx.x;
    float r = wave_reduce_sum(nll[q]);
    __shared__ float lds[8];
    const int wave = q >> 6, lane = q & 63;
    if (lane == 0) lds[wave] = r;
    __syncthreads();
    if (q == 0) {
        float tot = 0.f;
        #pragma unroll
        for (int w = 0; w < 8; ++w) tot += lds[w];
        out[0] = tot * (1.0f / (float)Q_DIM);
    }
}

extern "C" void kernel_launch(void* const* d_in, const int* in_sizes, int n_in,
                              void* d_out, int out_size, void* d_ws, size_t ws_size,
                              hipStream_t stream) {
    const float* supp  = (const float*)d_in[0];
    const float* query = (const float*)d_in[1];
    const int*   ys    = (const int*)d_in[2];
    float* out = (float*)d_out;

    float* ws    = (float*)d_ws;
    float* sp    = ws + WS_SP;
    float* qp    = ws + WS_QP;
    float* norms = ws + WS_NORMS;
    float* nll   = ws + WS_NLL;

    pool_kernel<<<S_DIM + Q_DIM, 512, 0, stream>>>(supp, query, sp, qp, norms);
    dot_kernel<<<Q_DIM / 8, 512, 0, stream>>>(sp, qp, norms, ys, out, nll);
    loss_kernel<<<1, 512, 0, stream>>>(nll, out);
}

// Round 3
// 54.726 us; speedup vs baseline: 1.2005x; 1.2005x over previous
//
#include <hip/hip_runtime.h>
#include <hip/hip_bf16.h>

// Problem constants (B=1, S=5, Q=512, T=64, D=2048)
#define S_DIM 5
#define Q_DIM 512
#define T_DIM 64
#define D_DIM 2048
#define EPS_CS 1e-8f

typedef float f32x4 __attribute__((ext_vector_type(4)));

// Workspace layout (floats):
//   sp  : [S_DIM][D_DIM] @ 0      (10240)
//   nll : [Q_DIM]        @ 10240  (512)
#define WS_SP  0
#define WS_NLL 10240

__device__ __forceinline__ float wave_reduce_sum(float v) {
    #pragma unroll
    for (int off = 32; off > 0; off >>= 1)
        v += __shfl_down(v, off, 64);
    return v;
}

__device__ __forceinline__ float dot4(f32x4 a, f32x4 b) {
    return a.x * b.x + a.y * b.y + a.z * b.z + a.w * b.w;
}

// Kernel 1: pool supp over T -> sp[s][d]. 40 blocks x 512 threads.
// block = (s, c): c-th chunk of 64 f32x4 slots; 8 t-groups of 8 t's each.
__global__ __launch_bounds__(512) void supp_pool_kernel(
    const float* __restrict__ supp, float* __restrict__ sp)
{
    const int s    = blockIdx.x >> 3;
    const int c    = blockIdx.x & 7;
    const int tg   = threadIdx.x >> 6;   // 8 t-groups
    const int lane = threadIdx.x & 63;
    const int slot = c * 64 + lane;      // f32x4 slot in [0, 512)

    const f32x4* base = (const f32x4*)(supp + (size_t)s * T_DIM * D_DIM);

    f32x4 acc = {0.f, 0.f, 0.f, 0.f};
    #pragma unroll
    for (int i = 0; i < 8; ++i) {
        const int t = tg * 8 + i;
        acc += base[t * (D_DIM / 4) + slot];
    }

    __shared__ f32x4 lds[8][64];
    lds[tg][lane] = acc;
    __syncthreads();
    if (tg == 0) {
        f32x4 tot = lds[0][lane];
        #pragma unroll
        for (int w = 1; w < 8; ++w) tot += lds[w][lane];
        tot *= (1.0f / (float)T_DIM);
        ((f32x4*)(sp + (size_t)s * D_DIM))[slot] = tot;
    }
}

// Kernel 2: one block per q. Pool query row over T (268 MB stream),
// dot vs 5 sp rows + self-dot + 5 sp self-dots (sn), then dist,
// (1-dist) output row, and nll[q]. 512 blocks x 512 threads.
__global__ __launch_bounds__(512) void query_fused_kernel(
    const float* __restrict__ query, const float* __restrict__ sp,
    const int* __restrict__ ys, float* __restrict__ out,
    float* __restrict__ nll)
{
    const int q   = blockIdx.x;
    const int tid = threadIdx.x;
    const f32x4* base = (const f32x4*)(query + (size_t)q * T_DIM * D_DIM);

    f32x4 acc = {0.f, 0.f, 0.f, 0.f};
    #pragma unroll 8
    for (int t = 0; t < T_DIM; ++t)
        acc += base[t * (D_DIM / 4) + tid];
    acc *= (1.0f / (float)T_DIM);

    // vals: [0..4] q.s_s, [5] q.q, [6..10] s_s.s_s
    float vals[11];
    vals[5] = dot4(acc, acc);
    #pragma unroll
    for (int s = 0; s < S_DIM; ++s) {
        f32x4 sv = ((const f32x4*)(sp + (size_t)s * D_DIM))[tid];
        vals[s]     = dot4(acc, sv);
        vals[6 + s] = dot4(sv, sv);
    }

    __shared__ float lds[8][11];
    const int wave = tid >> 6, lane = tid & 63;
    #pragma unroll
    for (int k = 0; k < 11; ++k) {
        float r = wave_reduce_sum(vals[k]);
        if (lane == 0) lds[wave][k] = r;
    }
    __syncthreads();

    if (tid == 0) {
        float tot[11];
        #pragma unroll
        for (int k = 0; k < 11; ++k) {
            float t = 0.f;
            #pragma unroll
            for (int w = 0; w < 8; ++w) t += lds[w][k];
            tot[k] = t;
        }
        const float qn = sqrtf(tot[5]);
        float dist[S_DIM];
        #pragma unroll
        for (int s = 0; s < S_DIM; ++s) {
            const float sn = sqrtf(tot[6 + s]);
            const float d  = tot[s] / fmaxf(qn * sn, EPS_CS);
            dist[s] = d;
            out[1 + (size_t)q * S_DIM + s] = 1.0f - d;
        }
        float m = dist[0];
        #pragma unroll
        for (int s = 1; s < S_DIM; ++s) m = fmaxf(m, dist[s]);
        float sum = 0.f;
        #pragma unroll
        for (int s = 0; s < S_DIM; ++s) sum += expf(dist[s] - m);
        const float lse = m + logf(sum);

        int y = ys[q];
        if (y < 0) y = 0;
        if (y >= S_DIM) y = S_DIM - 1;
        nll[q] = lse - dist[y];
    }
}

// Kernel 3: mean of nll over Q -> out[0]. 1 block x 512 threads.
__global__ __launch_bounds__(512) void loss_kernel(
    const float* __restrict__ nll, float* __restrict__ out)
{
    const int q = threadIdx.x;
    float r = wave_reduce_sum(nll[q]);
    __shared__ float lds[8];
    const int wave = q >> 6, lane = q & 63;
    if (lane == 0) lds[wave] = r;
    __syncthreads();
    if (q == 0) {
        float tot = 0.f;
        #pragma unroll
        for (int w = 0; w < 8; ++w) tot += lds[w];
        out[0] = tot * (1.0f / (float)Q_DIM);
    }
}

extern "C" void kernel_launch(void* const* d_in, const int* in_sizes, int n_in,
                              void* d_out, int out_size, void* d_ws, size_t ws_size,
                              hipStream_t stream) {
    const float* supp  = (const float*)d_in[0];
    const float* query = (const float*)d_in[1];
    const int*   ys    = (const int*)d_in[2];
    float* out = (float*)d_out;

    float* ws  = (float*)d_ws;
    float* sp  = ws + WS_SP;
    float* nll = ws + WS_NLL;

    supp_pool_kernel<<<S_DIM * 8, 512, 0, stream>>>(supp, sp);
    query_fused_kernel<<<Q_DIM, 512, 0, stream>>>(query, sp, ys, out, nll);
    loss_kernel<<<1, 512, 0, stream>>>(nll, out);
}